// Round 1
// baseline (1753.345 us; speedup 1.0000x reference)
//
#include <hip/hip_runtime.h>
#include <math.h>

// Problem constants
#define BATCH 128
#define NPER 400
#define EPG 6400
#define NEDGE 819200
#define F_IN 400
#define HD 128
#define K1 320
#define K2 256
#define K3 205

// ---------------- workspace layout ----------------
static constexpr size_t SZ_TREL = 51200ull * 128 * 4;           // 26,214,400
static constexpr size_t OFF_TREL = 0;
static constexpr size_t OFF_H    = OFF_TREL + SZ_TREL;
static constexpr size_t OFF_HP   = OFF_H + SZ_TREL;
static constexpr size_t OFF_SC   = OFF_HP + 40960ull * 128 * 4;
static constexpr size_t OFF_IDX  = OFF_SC + 51200ull * 4;
static constexpr size_t OFF_VALS = OFF_IDX + 40960ull * 4;
static constexpr size_t OFF_NEWID= OFF_VALS + 40960ull * 4;
static constexpr size_t OFF_ES   = OFF_NEWID + 51200ull * 4;
static constexpr size_t OFF_ED   = OFF_ES + (size_t)NEDGE * 4;
static constexpr size_t OFF_EM   = OFF_ED + (size_t)NEDGE * 4;
static constexpr size_t OFF_Z    = OFF_EM + (size_t)NEDGE * 4;

// ---------------- GEMM: C[M,128] = X[M,Kd] @ W[128,Kd]^T ----------------
// grid.x = M/64, block = 256. Kd must be a multiple of 16 (400, 128 ok).
__global__ __launch_bounds__(256) void gemm_xwt(const float* __restrict__ X,
                                                const float* __restrict__ W,
                                                float* __restrict__ C, int Kd) {
    __shared__ float As[64][16];   // [m][k]
    __shared__ float Bs[16][128];  // [k][n]
    const int tid = threadIdx.x;
    const int row0 = blockIdx.x * 64;
    const int tc = tid & 31;       // col group: cols tc*4 .. tc*4+3
    const int tr = tid >> 5;       // row group: rows tr*8 .. tr*8+7
    float acc[8][4];
#pragma unroll
    for (int i = 0; i < 8; i++)
#pragma unroll
        for (int j = 0; j < 4; j++) acc[i][j] = 0.f;

    for (int k0 = 0; k0 < Kd; k0 += 16) {
        // stage A tile 64x16 (float4 per thread)
        {
            int r = tid >> 2, kq = (tid & 3) << 2;
            float4 v = *(const float4*)&X[(size_t)(row0 + r) * Kd + k0 + kq];
            *(float4*)&As[r][kq] = v;
        }
        // stage B tile: W[n][k0..k0+16) -> Bs[k][n]
        {
            int n = tid >> 1, kh = (tid & 1) << 3;
            float4 v0 = *(const float4*)&W[(size_t)n * Kd + k0 + kh];
            float4 v1 = *(const float4*)&W[(size_t)n * Kd + k0 + kh + 4];
            Bs[kh + 0][n] = v0.x; Bs[kh + 1][n] = v0.y;
            Bs[kh + 2][n] = v0.z; Bs[kh + 3][n] = v0.w;
            Bs[kh + 4][n] = v1.x; Bs[kh + 5][n] = v1.y;
            Bs[kh + 6][n] = v1.z; Bs[kh + 7][n] = v1.w;
        }
        __syncthreads();
#pragma unroll
        for (int kk = 0; kk < 16; kk += 4) {
            float4 a4[8];
#pragma unroll
            for (int i = 0; i < 8; i++) a4[i] = *(const float4*)&As[tr * 8 + i][kk];
#pragma unroll
            for (int q = 0; q < 4; q++) {
                float4 b = *(const float4*)&Bs[kk + q][tc * 4];
#pragma unroll
                for (int i = 0; i < 8; i++) {
                    float a = ((const float*)&a4[i])[q];
                    acc[i][0] += a * b.x; acc[i][1] += a * b.y;
                    acc[i][2] += a * b.z; acc[i][3] += a * b.w;
                }
            }
        }
        __syncthreads();
    }
#pragma unroll
    for (int i = 0; i < 8; i++) {
        float4 v = make_float4(acc[i][0], acc[i][1], acc[i][2], acc[i][3]);
        *(float4*)&C[(size_t)(row0 + tr * 8 + i) * 128 + tc * 4] = v;
    }
}

// ---------------- Edge aggregation + combine + relu ----------------
// grid.x = BATCH*4 (4 feature chunks of 32), block = 1024.
// h (in/out) holds x@Wroot^T on entry; exit: h = relu(h + segsum(t_rel[src]) + bias)
__global__ __launch_bounds__(1024) void agg_combine(
    const float* __restrict__ t_rel,
    const int* __restrict__ es, const int* __restrict__ ed, const int* __restrict__ em,
    const int* __restrict__ gsrc, const int* __restrict__ gdst,
    const float* __restrict__ bias, float* __restrict__ h, int npg) {
    __shared__ float acc[NPER * 32];  // 51200 B, max npg=400
    const int g = blockIdx.x >> 2;
    const int c0 = (blockIdx.x & 3) << 5;

    for (int i = threadIdx.x; i < npg * 32; i += 1024) acc[i] = 0.f;
    __syncthreads();

    const int lane = threadIdx.x & 63;
    const int w = threadIdx.x >> 6;      // 0..15
    const int sub = lane >> 5;           // 0/1: which of 2 edges this half-wave does
    const int f = lane & 31;

    for (int it = 0; it < EPG / 32; ++it) {
        int e = it * 32 + w * 2 + sub;
        int eg = g * EPG + e;
        int srow, dl, m;
        if (es) {
            m = em[eg]; srow = g * npg + es[eg]; dl = ed[eg];
        } else {
            m = 1; srow = gsrc[eg]; dl = gdst[eg] - g * NPER;
        }
        if (m) {
            float v = t_rel[(size_t)srow * 128 + c0 + f];
            atomicAdd(&acc[dl * 32 + f], v);
        }
    }
    __syncthreads();

    for (int i = threadIdx.x; i < npg * 32; i += 1024) {
        int n = i >> 5, ff = i & 31;
        size_t o = (size_t)(g * npg + n) * 128 + c0 + ff;
        h[o] = fmaxf(h[o] + acc[i] + bias[c0 + ff], 0.f);
    }
}

// ---------------- scores: sc[i] = dot(h[i], pw) / (||pw|| + 1e-16) --------
// grid.x = M/4, block 256 (one wave per node)
__global__ __launch_bounds__(256) void score_kernel(const float* __restrict__ h,
                                                    const float* __restrict__ pw,
                                                    float* __restrict__ sc) {
    const int wid = (blockIdx.x * 256 + threadIdx.x) >> 6;
    const int lane = threadIdx.x & 63;
    float p0 = pw[lane], p1 = pw[64 + lane];
    float nrm = p0 * p0 + p1 * p1;
    float d = h[(size_t)wid * 128 + lane] * p0 + h[(size_t)wid * 128 + 64 + lane] * p1;
#pragma unroll
    for (int off = 32; off; off >>= 1) {
        d += __shfl_down(d, off, 64);
        nrm += __shfl_down(nrm, off, 64);
    }
    if (lane == 0) sc[wid] = d / (sqrtf(nrm) + 1e-16f);
}

// ---------------- topk per graph: exact bitonic sort of 512 ----------------
// grid = BATCH, block = 256
__device__ __forceinline__ bool rank_before(float as, int ai, float bs, int bi) {
    return (as > bs) || (as == bs && ai < bi);
}
__global__ __launch_bounds__(256) void topk_kernel(const float* __restrict__ sc,
                                                   int* __restrict__ idxo,
                                                   float* __restrict__ valso,
                                                   int* __restrict__ newid,
                                                   int npg, int k) {
    __shared__ float sk[512];
    __shared__ int si[512];
    const int g = blockIdx.x;
    for (int t = threadIdx.x; t < 512; t += 256) {
        sk[t] = (t < npg) ? sc[g * npg + t] : -INFINITY;
        si[t] = t;
    }
    __syncthreads();
    for (int size = 2; size <= 512; size <<= 1) {
        for (int stride = size >> 1; stride; stride >>= 1) {
            for (int i = threadIdx.x; i < 512; i += 256) {
                int j = i ^ stride;
                if (j > i) {
                    bool up = ((i & size) == 0);
                    float a = sk[i], b = sk[j];
                    int ai = si[i], bi = si[j];
                    bool doswap = up ? rank_before(b, bi, a, ai)
                                     : rank_before(a, ai, b, bi);
                    if (doswap) { sk[i] = b; sk[j] = a; si[i] = bi; si[j] = ai; }
                }
            }
            __syncthreads();
        }
    }
    for (int t = threadIdx.x; t < 512; t += 256) {
        if (t < npg) {
            int orig = si[t];
            newid[g * npg + orig] = (t < k) ? t : -1;
            if (t < k) { idxo[g * k + t] = orig; valso[g * k + t] = sk[t]; }
        }
    }
}

// ---------------- gather + gate: hp[b] = h[g*npg+idx[b]] * tanh(vals[b]) ----
// grid = BATCH*k, block = 128
__global__ __launch_bounds__(128) void gather_gate(const float* __restrict__ h,
                                                   const int* __restrict__ idx,
                                                   const float* __restrict__ vals,
                                                   float* __restrict__ hp,
                                                   int npg, int k) {
    int b = blockIdx.x;
    int g = b / k;
    int orig = idx[b];
    float t = tanhf(vals[b]);
    hp[(size_t)b * 128 + threadIdx.x] =
        h[(size_t)(g * npg + orig) * 128 + threadIdx.x] * t;
}

// ---------------- edge remap (in-place capable) ----------------
// grid = NEDGE/256
__global__ __launch_bounds__(256) void remap_edges(const int* __restrict__ gsrc,
                                                   const int* __restrict__ gdst,
                                                   int* __restrict__ es,
                                                   int* __restrict__ ed,
                                                   int* __restrict__ em,
                                                   const int* __restrict__ newid,
                                                   int npg, int first) {
    int e = blockIdx.x * 256 + threadIdx.x;
    int g = e / EPG;
    int sl, dl, m;
    if (first) { sl = gsrc[e] - g * NPER; dl = gdst[e] - g * NPER; m = 1; }
    else       { sl = es[e]; dl = ed[e]; m = em[e]; }
    int ns = newid[g * npg + sl];
    int nd = newid[g * npg + dl];
    int keep = (m && ns >= 0 && nd >= 0) ? 1 : 0;
    es[e] = keep ? ns : 0;
    ed[e] = keep ? nd : 0;
    em[e] = keep;
}

// ---------------- readout (already-gated features) ----------------
// grid = BATCH, block = 128; z[g,0:128] += max_j, z[g,128:256] += mean_j
__global__ __launch_bounds__(128) void readout_plain(const float* __restrict__ hp,
                                                     float* __restrict__ z, int k) {
    const int g = blockIdx.x, f = threadIdx.x;
    float mx = -INFINITY, sm = 0.f;
    const float* base = &hp[(size_t)g * k * 128 + f];
    for (int j = 0; j < k; j++) {
        float v = base[(size_t)j * 128];
        mx = fmaxf(mx, v);
        sm += v;
    }
    z[g * 256 + f] += mx;
    z[g * 256 + 128 + f] += sm / (float)k;
}

// readout with gather+gate fused (stage 3, no materialized pooled features)
__global__ __launch_bounds__(128) void readout_gather(const float* __restrict__ h,
                                                      const int* __restrict__ idx,
                                                      const float* __restrict__ vals,
                                                      float* __restrict__ z,
                                                      int npg, int k) {
    __shared__ float tg[256];
    const int g = blockIdx.x, f = threadIdx.x;
    for (int j = f; j < k; j += 128) tg[j] = tanhf(vals[g * k + j]);
    __syncthreads();
    float mx = -INFINITY, sm = 0.f;
    for (int j = 0; j < k; j++) {
        int orig = idx[g * k + j];
        float v = h[(size_t)(g * npg + orig) * 128 + f] * tg[j];
        mx = fmaxf(mx, v);
        sm += v;
    }
    z[g * 256 + f] += mx;
    z[g * 256 + 128 + f] += sm / (float)k;
}

// ---------------- MLP head + log_softmax ----------------
// grid = BATCH, block = 256
__global__ __launch_bounds__(256) void mlp_head(const float* __restrict__ z,
                                                const float* __restrict__ W1,
                                                const float* __restrict__ bl1,
                                                const float* __restrict__ W2,
                                                const float* __restrict__ bl2,
                                                const float* __restrict__ W3,
                                                const float* __restrict__ bl3,
                                                float* __restrict__ out) {
    __shared__ float zs[256], l1[128], l2[64];
    const int g = blockIdx.x, t = threadIdx.x;
    zs[t] = z[g * 256 + t];
    __syncthreads();
    if (t < 128) {
        float s = bl1[t];
        const float* w = &W1[t * 256];
        for (int i = 0; i < 256; i++) s += w[i] * zs[i];
        l1[t] = fmaxf(s, 0.f);
    }
    __syncthreads();
    if (t < 64) {
        float s = bl2[t];
        const float* w = &W2[t * 128];
        for (int i = 0; i < 128; i++) s += w[i] * l1[i];
        l2[t] = fmaxf(s, 0.f);
    }
    __syncthreads();
    if (t == 0) {
        float a = bl3[0], b = bl3[1];
        for (int i = 0; i < 64; i++) { a += W3[i] * l2[i]; b += W3[64 + i] * l2[i]; }
        float m = fmaxf(a, b);
        float lse = m + logf(expf(a - m) + expf(b - m));
        out[g * 2 + 0] = a - lse;
        out[g * 2 + 1] = b - lse;
    }
}

// ---------------- launch ----------------
extern "C" void kernel_launch(void* const* d_in, const int* in_sizes, int n_in,
                              void* d_out, int out_size, void* d_ws, size_t ws_size,
                              hipStream_t stream) {
    const float* x        = (const float*)d_in[0];
    const int*   edge_src = (const int*)d_in[1];
    const int*   edge_dst = (const int*)d_in[2];
    const float* Wrel1 = (const float*)d_in[4];
    const float* Wroot1= (const float*)d_in[5];
    const float* b1    = (const float*)d_in[6];
    const float* pw1   = (const float*)d_in[7];
    const float* Wrel2 = (const float*)d_in[8];
    const float* Wroot2= (const float*)d_in[9];
    const float* b2    = (const float*)d_in[10];
    const float* pw2   = (const float*)d_in[11];
    const float* Wrel3 = (const float*)d_in[12];
    const float* Wroot3= (const float*)d_in[13];
    const float* b3    = (const float*)d_in[14];
    const float* pw3   = (const float*)d_in[15];
    const float* W1    = (const float*)d_in[16];
    const float* bl1   = (const float*)d_in[17];
    const float* W2    = (const float*)d_in[18];
    const float* bl2   = (const float*)d_in[19];
    const float* W3    = (const float*)d_in[20];
    const float* bl3   = (const float*)d_in[21];

    char* ws = (char*)d_ws;
    float* t_rel = (float*)(ws + OFF_TREL);
    float* h     = (float*)(ws + OFF_H);
    float* hp    = (float*)(ws + OFF_HP);
    float* sc    = (float*)(ws + OFF_SC);
    int*   idx   = (int*)(ws + OFF_IDX);
    float* vals  = (float*)(ws + OFF_VALS);
    int*   newid = (int*)(ws + OFF_NEWID);
    int*   es    = (int*)(ws + OFF_ES);
    int*   ed    = (int*)(ws + OFF_ED);
    int*   em    = (int*)(ws + OFF_EM);
    float* z     = (float*)(ws + OFF_Z);

    hipMemsetAsync(z, 0, 128ull * 256 * 4, stream);

    // ---------- layer 1 ----------
    gemm_xwt<<<800, 256, 0, stream>>>(x, Wrel1, t_rel, F_IN);
    gemm_xwt<<<800, 256, 0, stream>>>(x, Wroot1, h, F_IN);
    agg_combine<<<BATCH * 4, 1024, 0, stream>>>(t_rel, nullptr, nullptr, nullptr,
                                                edge_src, edge_dst, b1, h, NPER);
    score_kernel<<<51200 / 4, 256, 0, stream>>>(h, pw1, sc);
    topk_kernel<<<BATCH, 256, 0, stream>>>(sc, idx, vals, newid, NPER, K1);
    gather_gate<<<BATCH * K1, 128, 0, stream>>>(h, idx, vals, hp, NPER, K1);
    remap_edges<<<NEDGE / 256, 256, 0, stream>>>(edge_src, edge_dst, es, ed, em,
                                                 newid, NPER, 1);
    readout_plain<<<BATCH, 128, 0, stream>>>(hp, z, K1);

    // ---------- layer 2 ----------
    gemm_xwt<<<640, 256, 0, stream>>>(hp, Wrel2, t_rel, HD);
    gemm_xwt<<<640, 256, 0, stream>>>(hp, Wroot2, h, HD);
    agg_combine<<<BATCH * 4, 1024, 0, stream>>>(t_rel, es, ed, em,
                                                nullptr, nullptr, b2, h, K1);
    score_kernel<<<40960 / 4, 256, 0, stream>>>(h, pw2, sc);
    topk_kernel<<<BATCH, 256, 0, stream>>>(sc, idx, vals, newid, K1, K2);
    gather_gate<<<BATCH * K2, 128, 0, stream>>>(h, idx, vals, hp, K1, K2);
    remap_edges<<<NEDGE / 256, 256, 0, stream>>>(nullptr, nullptr, es, ed, em,
                                                 newid, K1, 0);
    readout_plain<<<BATCH, 128, 0, stream>>>(hp, z, K2);

    // ---------- layer 3 ----------
    gemm_xwt<<<512, 256, 0, stream>>>(hp, Wrel3, t_rel, HD);
    gemm_xwt<<<512, 256, 0, stream>>>(hp, Wroot3, h, HD);
    agg_combine<<<BATCH * 4, 1024, 0, stream>>>(t_rel, es, ed, em,
                                                nullptr, nullptr, b3, h, K2);
    score_kernel<<<32768 / 4, 256, 0, stream>>>(h, pw3, sc);
    topk_kernel<<<BATCH, 256, 0, stream>>>(sc, idx, vals, newid, K2, K3);
    readout_gather<<<BATCH, 128, 0, stream>>>(h, idx, vals, z, K2, K3);

    // ---------- MLP head ----------
    mlp_head<<<BATCH, 256, 0, stream>>>(z, W1, bl1, W2, bl2, W3, bl3, (float*)d_out);
}

// Round 2
// 878.703 us; speedup vs baseline: 1.9954x; 1.9954x over previous
//
#include <hip/hip_runtime.h>
#include <math.h>

// Problem constants
#define BATCH 128
#define NPER 400
#define EPG 6400
#define NEDGE 819200
#define F_IN 400
#define HD 128
#define K1 320
#define K2 256
#define K3 205

// ---------------- workspace layout ----------------
static constexpr size_t SZ_TREL = 51200ull * 128 * 4;           // 26,214,400
static constexpr size_t OFF_TREL = 0;
static constexpr size_t OFF_H    = OFF_TREL + SZ_TREL;
static constexpr size_t OFF_HP   = OFF_H + SZ_TREL;
static constexpr size_t OFF_SC   = OFF_HP + 40960ull * 128 * 4;
static constexpr size_t OFF_IDX  = OFF_SC + 51200ull * 4;
static constexpr size_t OFF_VALS = OFF_IDX + 40960ull * 4;
static constexpr size_t OFF_NEWID= OFF_VALS + 40960ull * 4;
static constexpr size_t OFF_ES   = OFF_NEWID + 51200ull * 4;
static constexpr size_t OFF_ED   = OFF_ES + (size_t)NEDGE * 4;
static constexpr size_t OFF_EM   = OFF_ED + (size_t)NEDGE * 4;
static constexpr size_t OFF_Z    = OFF_EM + (size_t)NEDGE * 4;
static constexpr size_t OFF_COFF = OFF_Z + 128ull * 256 * 4;
static constexpr size_t OFF_CDEG = OFF_COFF + 51200ull * 4;
static constexpr size_t OFF_CSRC = OFF_CDEG + 51200ull * 4;

// ---------------- GEMM: C[M,128] = X[M,Kd] @ W[128,Kd]^T ----------------
// grid.x = M/64, block = 256. Kd must be a multiple of 16 (400, 128 ok).
__global__ __launch_bounds__(256) void gemm_xwt(const float* __restrict__ X,
                                                const float* __restrict__ W,
                                                float* __restrict__ C, int Kd) {
    __shared__ float As[64][16];   // [m][k]
    __shared__ float Bs[16][128];  // [k][n]
    const int tid = threadIdx.x;
    const int row0 = blockIdx.x * 64;
    const int tc = tid & 31;       // col group: cols tc*4 .. tc*4+3
    const int tr = tid >> 5;       // row group: rows tr*8 .. tr*8+7
    float acc[8][4];
#pragma unroll
    for (int i = 0; i < 8; i++)
#pragma unroll
        for (int j = 0; j < 4; j++) acc[i][j] = 0.f;

    for (int k0 = 0; k0 < Kd; k0 += 16) {
        // stage A tile 64x16 (float4 per thread)
        {
            int r = tid >> 2, kq = (tid & 3) << 2;
            float4 v = *(const float4*)&X[(size_t)(row0 + r) * Kd + k0 + kq];
            *(float4*)&As[r][kq] = v;
        }
        // stage B tile: W[n][k0..k0+16) -> Bs[k][n]
        {
            int n = tid >> 1, kh = (tid & 1) << 3;
            float4 v0 = *(const float4*)&W[(size_t)n * Kd + k0 + kh];
            float4 v1 = *(const float4*)&W[(size_t)n * Kd + k0 + kh + 4];
            Bs[kh + 0][n] = v0.x; Bs[kh + 1][n] = v0.y;
            Bs[kh + 2][n] = v0.z; Bs[kh + 3][n] = v0.w;
            Bs[kh + 4][n] = v1.x; Bs[kh + 5][n] = v1.y;
            Bs[kh + 6][n] = v1.z; Bs[kh + 7][n] = v1.w;
        }
        __syncthreads();
#pragma unroll
        for (int kk = 0; kk < 16; kk += 4) {
            float4 a4[8];
#pragma unroll
            for (int i = 0; i < 8; i++) a4[i] = *(const float4*)&As[tr * 8 + i][kk];
#pragma unroll
            for (int q = 0; q < 4; q++) {
                float4 b = *(const float4*)&Bs[kk + q][tc * 4];
#pragma unroll
                for (int i = 0; i < 8; i++) {
                    float a = ((const float*)&a4[i])[q];
                    acc[i][0] += a * b.x; acc[i][1] += a * b.y;
                    acc[i][2] += a * b.z; acc[i][3] += a * b.w;
                }
            }
        }
        __syncthreads();
    }
#pragma unroll
    for (int i = 0; i < 8; i++) {
        float4 v = make_float4(acc[i][0], acc[i][1], acc[i][2], acc[i][3]);
        *(float4*)&C[(size_t)(row0 + tr * 8 + i) * 128 + tc * 4] = v;
    }
}

// ---------------- CSR build: one block per graph ----------------
// Counts in-degree per dst, exclusive-scans, fills per-graph edge list.
// Masked edges are never inserted (emask==0 => contributes 0).
__global__ __launch_bounds__(1024) void csr_build(
    const int* __restrict__ es, const int* __restrict__ ed, const int* __restrict__ em,
    const int* __restrict__ gsrc, const int* __restrict__ gdst,
    int* __restrict__ csr_off, int* __restrict__ csr_deg, int* __restrict__ csr_src,
    int npg, int first) {
    __shared__ int cnt[NPER];
    __shared__ int cur[NPER];
    __shared__ int sscan[512];
    const int g = blockIdx.x;
    const int t = threadIdx.x;

    for (int i = t; i < npg; i += 1024) cnt[i] = 0;
    __syncthreads();

    // count
    for (int e = t; e < EPG; e += 1024) {
        int eg = g * EPG + e;
        int dl, keep;
        if (first) { dl = gdst[eg] - g * NPER; keep = 1; }
        else       { keep = em[eg]; dl = ed[eg]; }
        if (keep) atomicAdd(&cnt[dl], 1);
    }
    __syncthreads();

    // inclusive scan over 512 (padded)
    if (t < 512) sscan[t] = (t < npg) ? cnt[t] : 0;
    __syncthreads();
    for (int d = 1; d < 512; d <<= 1) {
        int v = 0;
        if (t < 512 && t >= d) v = sscan[t - d];
        __syncthreads();
        if (t < 512 && t >= d) sscan[t] += v;
        __syncthreads();
    }

    if (t < npg) {
        int excl = (t == 0) ? 0 : sscan[t - 1];
        int st = g * EPG + excl;
        csr_off[g * npg + t] = st;
        csr_deg[g * npg + t] = cnt[t];
        cur[t] = st;
    }
    __syncthreads();

    // fill
    for (int e = t; e < EPG; e += 1024) {
        int eg = g * EPG + e;
        int dl, keep, srow;
        if (first) { dl = gdst[eg] - g * NPER; keep = 1; srow = gsrc[eg]; }
        else       { keep = em[eg]; dl = ed[eg]; srow = g * npg + es[eg]; }
        if (keep) {
            int slot = atomicAdd(&cur[dl], 1);
            csr_src[slot] = srow;
        }
    }
}

// ---------------- Aggregation (gather) + combine + relu ----------------
// One wave per destination node; lane covers features {2*lane, 2*lane+1}.
// h holds x@Wroot^T on entry; exit: h = relu(h + segsum(t_rel[src]) + bias)
__global__ __launch_bounds__(256) void agg_gather(
    const float* __restrict__ t_rel,
    const int* __restrict__ csr_off, const int* __restrict__ csr_deg,
    const int* __restrict__ csr_src,
    const float* __restrict__ bias, float* __restrict__ h, int total_nodes) {
    const int wid = (blockIdx.x * 256 + threadIdx.x) >> 6;   // node
    const int lane = threadIdx.x & 63;
    if (wid >= total_nodes) return;
    const int start = csr_off[wid];
    const int deg = csr_deg[wid];
    float a0 = 0.f, a1 = 0.f;
    for (int e = 0; e < deg; e++) {
        int srow = csr_src[start + e];
        float2 v = *(const float2*)&t_rel[(size_t)srow * 128 + lane * 2];
        a0 += v.x; a1 += v.y;
    }
    float2 bb = *(const float2*)&bias[lane * 2];
    size_t o = (size_t)wid * 128 + lane * 2;
    float2 hv = *(const float2*)&h[o];
    hv.x = fmaxf(hv.x + a0 + bb.x, 0.f);
    hv.y = fmaxf(hv.y + a1 + bb.y, 0.f);
    *(float2*)&h[o] = hv;
}

// ---------------- scores: sc[i] = dot(h[i], pw) / (||pw|| + 1e-16) --------
// grid.x = M/4, block 256 (one wave per node)
__global__ __launch_bounds__(256) void score_kernel(const float* __restrict__ h,
                                                    const float* __restrict__ pw,
                                                    float* __restrict__ sc) {
    const int wid = (blockIdx.x * 256 + threadIdx.x) >> 6;
    const int lane = threadIdx.x & 63;
    float p0 = pw[lane], p1 = pw[64 + lane];
    float nrm = p0 * p0 + p1 * p1;
    float d = h[(size_t)wid * 128 + lane] * p0 + h[(size_t)wid * 128 + 64 + lane] * p1;
#pragma unroll
    for (int off = 32; off; off >>= 1) {
        d += __shfl_down(d, off, 64);
        nrm += __shfl_down(nrm, off, 64);
    }
    if (lane == 0) sc[wid] = d / (sqrtf(nrm) + 1e-16f);
}

// ---------------- topk per graph: exact bitonic sort of 512 ----------------
// grid = BATCH, block = 256
__device__ __forceinline__ bool rank_before(float as, int ai, float bs, int bi) {
    return (as > bs) || (as == bs && ai < bi);
}
__global__ __launch_bounds__(256) void topk_kernel(const float* __restrict__ sc,
                                                   int* __restrict__ idxo,
                                                   float* __restrict__ valso,
                                                   int* __restrict__ newid,
                                                   int npg, int k) {
    __shared__ float sk[512];
    __shared__ int si[512];
    const int g = blockIdx.x;
    for (int t = threadIdx.x; t < 512; t += 256) {
        sk[t] = (t < npg) ? sc[g * npg + t] : -INFINITY;
        si[t] = t;
    }
    __syncthreads();
    for (int size = 2; size <= 512; size <<= 1) {
        for (int stride = size >> 1; stride; stride >>= 1) {
            for (int i = threadIdx.x; i < 512; i += 256) {
                int j = i ^ stride;
                if (j > i) {
                    bool up = ((i & size) == 0);
                    float a = sk[i], b = sk[j];
                    int ai = si[i], bi = si[j];
                    bool doswap = up ? rank_before(b, bi, a, ai)
                                     : rank_before(a, ai, b, bi);
                    if (doswap) { sk[i] = b; sk[j] = a; si[i] = bi; si[j] = ai; }
                }
            }
            __syncthreads();
        }
    }
    for (int t = threadIdx.x; t < 512; t += 256) {
        if (t < npg) {
            int orig = si[t];
            newid[g * npg + orig] = (t < k) ? t : -1;
            if (t < k) { idxo[g * k + t] = orig; valso[g * k + t] = sk[t]; }
        }
    }
}

// ---------------- gather + gate: hp[b] = h[g*npg+idx[b]] * tanh(vals[b]) ----
// grid = BATCH*k, block = 128
__global__ __launch_bounds__(128) void gather_gate(const float* __restrict__ h,
                                                   const int* __restrict__ idx,
                                                   const float* __restrict__ vals,
                                                   float* __restrict__ hp,
                                                   int npg, int k) {
    int b = blockIdx.x;
    int g = b / k;
    int orig = idx[b];
    float t = tanhf(vals[b]);
    hp[(size_t)b * 128 + threadIdx.x] =
        h[(size_t)(g * npg + orig) * 128 + threadIdx.x] * t;
}

// ---------------- edge remap (in-place capable) ----------------
// grid = NEDGE/256
__global__ __launch_bounds__(256) void remap_edges(const int* __restrict__ gsrc,
                                                   const int* __restrict__ gdst,
                                                   int* __restrict__ es,
                                                   int* __restrict__ ed,
                                                   int* __restrict__ em,
                                                   const int* __restrict__ newid,
                                                   int npg, int first) {
    int e = blockIdx.x * 256 + threadIdx.x;
    int g = e / EPG;
    int sl, dl, m;
    if (first) { sl = gsrc[e] - g * NPER; dl = gdst[e] - g * NPER; m = 1; }
    else       { sl = es[e]; dl = ed[e]; m = em[e]; }
    int ns = newid[g * npg + sl];
    int nd = newid[g * npg + dl];
    int keep = (m && ns >= 0 && nd >= 0) ? 1 : 0;
    es[e] = keep ? ns : 0;
    ed[e] = keep ? nd : 0;
    em[e] = keep;
}

// ---------------- readout (already-gated features) ----------------
// grid = BATCH, block = 128; z[g,0:128] += max_j, z[g,128:256] += mean_j
__global__ __launch_bounds__(128) void readout_plain(const float* __restrict__ hp,
                                                     float* __restrict__ z, int k) {
    const int g = blockIdx.x, f = threadIdx.x;
    float mx = -INFINITY, sm = 0.f;
    const float* base = &hp[(size_t)g * k * 128 + f];
    for (int j = 0; j < k; j++) {
        float v = base[(size_t)j * 128];
        mx = fmaxf(mx, v);
        sm += v;
    }
    z[g * 256 + f] += mx;
    z[g * 256 + 128 + f] += sm / (float)k;
}

// readout with gather+gate fused (stage 3, no materialized pooled features)
__global__ __launch_bounds__(128) void readout_gather(const float* __restrict__ h,
                                                      const int* __restrict__ idx,
                                                      const float* __restrict__ vals,
                                                      float* __restrict__ z,
                                                      int npg, int k) {
    __shared__ float tg[256];
    const int g = blockIdx.x, f = threadIdx.x;
    for (int j = f; j < k; j += 128) tg[j] = tanhf(vals[g * k + j]);
    __syncthreads();
    float mx = -INFINITY, sm = 0.f;
    for (int j = 0; j < k; j++) {
        int orig = idx[g * k + j];
        float v = h[(size_t)(g * npg + orig) * 128 + f] * tg[j];
        mx = fmaxf(mx, v);
        sm += v;
    }
    z[g * 256 + f] += mx;
    z[g * 256 + 128 + f] += sm / (float)k;
}

// ---------------- MLP head + log_softmax ----------------
// grid = BATCH, block = 256
__global__ __launch_bounds__(256) void mlp_head(const float* __restrict__ z,
                                                const float* __restrict__ W1,
                                                const float* __restrict__ bl1,
                                                const float* __restrict__ W2,
                                                const float* __restrict__ bl2,
                                                const float* __restrict__ W3,
                                                const float* __restrict__ bl3,
                                                float* __restrict__ out) {
    __shared__ float zs[256], l1[128], l2[64];
    const int g = blockIdx.x, t = threadIdx.x;
    zs[t] = z[g * 256 + t];
    __syncthreads();
    if (t < 128) {
        float s = bl1[t];
        const float* w = &W1[t * 256];
        for (int i = 0; i < 256; i++) s += w[i] * zs[i];
        l1[t] = fmaxf(s, 0.f);
    }
    __syncthreads();
    if (t < 64) {
        float s = bl2[t];
        const float* w = &W2[t * 128];
        for (int i = 0; i < 128; i++) s += w[i] * l1[i];
        l2[t] = fmaxf(s, 0.f);
    }
    __syncthreads();
    if (t == 0) {
        float a = bl3[0], b = bl3[1];
        for (int i = 0; i < 64; i++) { a += W3[i] * l2[i]; b += W3[64 + i] * l2[i]; }
        float m = fmaxf(a, b);
        float lse = m + logf(expf(a - m) + expf(b - m));
        out[g * 2 + 0] = a - lse;
        out[g * 2 + 1] = b - lse;
    }
}

// ---------------- launch ----------------
extern "C" void kernel_launch(void* const* d_in, const int* in_sizes, int n_in,
                              void* d_out, int out_size, void* d_ws, size_t ws_size,
                              hipStream_t stream) {
    const float* x        = (const float*)d_in[0];
    const int*   edge_src = (const int*)d_in[1];
    const int*   edge_dst = (const int*)d_in[2];
    const float* Wrel1 = (const float*)d_in[4];
    const float* Wroot1= (const float*)d_in[5];
    const float* b1    = (const float*)d_in[6];
    const float* pw1   = (const float*)d_in[7];
    const float* Wrel2 = (const float*)d_in[8];
    const float* Wroot2= (const float*)d_in[9];
    const float* b2    = (const float*)d_in[10];
    const float* pw2   = (const float*)d_in[11];
    const float* Wrel3 = (const float*)d_in[12];
    const float* Wroot3= (const float*)d_in[13];
    const float* b3    = (const float*)d_in[14];
    const float* pw3   = (const float*)d_in[15];
    const float* W1    = (const float*)d_in[16];
    const float* bl1   = (const float*)d_in[17];
    const float* W2    = (const float*)d_in[18];
    const float* bl2   = (const float*)d_in[19];
    const float* W3    = (const float*)d_in[20];
    const float* bl3   = (const float*)d_in[21];

    char* ws = (char*)d_ws;
    float* t_rel = (float*)(ws + OFF_TREL);
    float* h     = (float*)(ws + OFF_H);
    float* hp    = (float*)(ws + OFF_HP);
    float* sc    = (float*)(ws + OFF_SC);
    int*   idx   = (int*)(ws + OFF_IDX);
    float* vals  = (float*)(ws + OFF_VALS);
    int*   newid = (int*)(ws + OFF_NEWID);
    int*   es    = (int*)(ws + OFF_ES);
    int*   ed    = (int*)(ws + OFF_ED);
    int*   em    = (int*)(ws + OFF_EM);
    float* z     = (float*)(ws + OFF_Z);
    int*   coff  = (int*)(ws + OFF_COFF);
    int*   cdeg  = (int*)(ws + OFF_CDEG);
    int*   csrc  = (int*)(ws + OFF_CSRC);

    hipMemsetAsync(z, 0, 128ull * 256 * 4, stream);

    // ---------- layer 1 ----------
    csr_build<<<BATCH, 1024, 0, stream>>>(nullptr, nullptr, nullptr,
                                          edge_src, edge_dst, coff, cdeg, csrc,
                                          NPER, 1);
    gemm_xwt<<<800, 256, 0, stream>>>(x, Wrel1, t_rel, F_IN);
    gemm_xwt<<<800, 256, 0, stream>>>(x, Wroot1, h, F_IN);
    agg_gather<<<51200 / 4, 256, 0, stream>>>(t_rel, coff, cdeg, csrc, b1, h, 51200);
    score_kernel<<<51200 / 4, 256, 0, stream>>>(h, pw1, sc);
    topk_kernel<<<BATCH, 256, 0, stream>>>(sc, idx, vals, newid, NPER, K1);
    gather_gate<<<BATCH * K1, 128, 0, stream>>>(h, idx, vals, hp, NPER, K1);
    remap_edges<<<NEDGE / 256, 256, 0, stream>>>(edge_src, edge_dst, es, ed, em,
                                                 newid, NPER, 1);
    readout_plain<<<BATCH, 128, 0, stream>>>(hp, z, K1);

    // ---------- layer 2 ----------
    csr_build<<<BATCH, 1024, 0, stream>>>(es, ed, em, nullptr, nullptr,
                                          coff, cdeg, csrc, K1, 0);
    gemm_xwt<<<640, 256, 0, stream>>>(hp, Wrel2, t_rel, HD);
    gemm_xwt<<<640, 256, 0, stream>>>(hp, Wroot2, h, HD);
    agg_gather<<<40960 / 4, 256, 0, stream>>>(t_rel, coff, cdeg, csrc, b2, h, 40960);
    score_kernel<<<40960 / 4, 256, 0, stream>>>(h, pw2, sc);
    topk_kernel<<<BATCH, 256, 0, stream>>>(sc, idx, vals, newid, K1, K2);
    gather_gate<<<BATCH * K2, 128, 0, stream>>>(h, idx, vals, hp, K1, K2);
    remap_edges<<<NEDGE / 256, 256, 0, stream>>>(nullptr, nullptr, es, ed, em,
                                                 newid, K1, 0);
    readout_plain<<<BATCH, 128, 0, stream>>>(hp, z, K2);

    // ---------- layer 3 ----------
    csr_build<<<BATCH, 1024, 0, stream>>>(es, ed, em, nullptr, nullptr,
                                          coff, cdeg, csrc, K2, 0);
    gemm_xwt<<<512, 256, 0, stream>>>(hp, Wrel3, t_rel, HD);
    gemm_xwt<<<512, 256, 0, stream>>>(hp, Wroot3, h, HD);
    agg_gather<<<32768 / 4, 256, 0, stream>>>(t_rel, coff, cdeg, csrc, b3, h, 32768);
    score_kernel<<<32768 / 4, 256, 0, stream>>>(h, pw3, sc);
    topk_kernel<<<BATCH, 256, 0, stream>>>(sc, idx, vals, newid, K2, K3);
    readout_gather<<<BATCH, 128, 0, stream>>>(h, idx, vals, z, K2, K3);

    // ---------- MLP head ----------
    mlp_head<<<BATCH, 256, 0, stream>>>(z, W1, bl1, W2, bl2, W3, bl3, (float*)d_out);
}